// Round 6
// baseline (12912.822 us; speedup 1.0000x reference)
//
#include <hip/hip_runtime.h>
#include <stdint.h>

#define Tt 1024
#define Bt 128
#define Vt 256
#define TS 32768                       // shorts per t-slice
#define MOFF ((size_t)2 * Tt * TS)     // mirror offset in shorts (128MB)

typedef __attribute__((ext_vector_type(8))) short bf16x8;
typedef __attribute__((ext_vector_type(4))) float f32x4;
typedef __attribute__((ext_vector_type(4))) int i32x4;

#define MFMA(a, b, c) __builtin_amdgcn_mfma_f32_16x16x32_bf16(a, b, c, 0, 0, 0)

// Sentinel = bf16 +NaN (0x7FFF): f2bf of finite h in (-1,1) can never produce it.
#define SENT 0x7FFF

// ---- layout ----------------------------------------------------------------
// 128 WGs: bid = (layer*8 + cgrp)*8 + rgrp.  bid%8 = rgrp -> XCD (round-robin
// dispatch): ALL WGs of one batch-group (both layers, all col-groups) share an
// XCD, so the whole recurrence exchanges through that XCD's L2 (sc0), never
// the MALL.  mode=1 adds a MALL mirror (sc0 sc1) as a placement-safe fallback.
// h[t] slice: [rgrp(8)][cgrp(8)][row(16)][col(32)] shorts;
//   tile = 1KB; producer wave stores 256B coalesced; consumer A-frag
//   (row=ln, cols kb*32+q*8) reads are fully coalesced per tile.

__device__ __forceinline__ unsigned short f2bf(float f) {
    unsigned u = __builtin_bit_cast(unsigned, f);
    u += 0x7fffu + ((u >> 16) & 1u);
    return (unsigned short)(u >> 16);
}
__device__ __forceinline__ float sigm(float x) {
    return __builtin_amdgcn_rcpf(1.f + __expf(-x));
}
__device__ __forceinline__ float tanh_f(float x) {
    float e = __expf(-2.f * fabsf(x));
    float t = (1.f - e) * __builtin_amdgcn_rcpf(1.f + e);
    return copysignf(t, x);
}

// 16B coherent loads. SYS=false: sc0 (XCD-L2 scope). SYS=true: sc0 sc1 (MALL).
template <int OFF, bool SYS>
__device__ __forceinline__ bf16x8 ld16(const unsigned short* p) {
    bf16x8 d;
    if constexpr (SYS)
        asm volatile("global_load_dwordx4 %0, %1, off offset:%c2 sc0 sc1"
                     : "=v"(d) : "v"(p), "i"(OFF));
    else
        asm volatile("global_load_dwordx4 %0, %1, off offset:%c2 sc0"
                     : "=v"(d) : "v"(p), "i"(OFF));
    return d;
}
template <bool SYS>
__device__ __forceinline__ bf16x8 ld16p(const unsigned short* p) {
    bf16x8 d;
    if constexpr (SYS)
        asm volatile("global_load_dwordx4 %0, %1, off sc0 sc1" : "=v"(d) : "v"(p));
    else
        asm volatile("global_load_dwordx4 %0, %1, off sc0" : "=v"(d) : "v"(p));
    return d;
}
template <bool SYS>
__device__ __forceinline__ void ldset(bf16x8* d, const unsigned short* P) {
    const unsigned short* P2 = P + 2048;
    d[0] = ld16<0, SYS>(P);  d[1] = ld16<1024, SYS>(P);
    d[2] = ld16<2048, SYS>(P); d[3] = ld16<3072, SYS>(P);
    d[4] = ld16<0, SYS>(P2); d[5] = ld16<1024, SYS>(P2);
    d[6] = ld16<2048, SYS>(P2); d[7] = ld16<3072, SYS>(P2);
}

__device__ __forceinline__ void vm_drain() {
    asm volatile("s_waitcnt vmcnt(0)" ::: "memory");
    __builtin_amdgcn_sched_barrier(0);  // rule #18
}

__device__ __forceinline__ int fdirty(bf16x8 f) {
    i32x4 d = __builtin_bit_cast(i32x4, f);
    return ((d.x & 0xFFFF) == SENT) | ((d.z & 0xFFFF) == SENT);
}

// Sentinel poll, per-kb dirty reload. mode=1: local sc0 first, switch to the
// MALL mirror after 16 failed rounds (placement-safe). mode=0: always MALL.
__device__ __forceinline__ void pollset(bf16x8 (&d)[8], const unsigned short* P,
                                        int mode) {
    unsigned pm = 0xffu;
    int tries = 0;
    bool sys = (mode == 0);
    const unsigned short* PP = P;
    for (;;) {
        vm_drain();
        unsigned nm = 0;
#pragma unroll
        for (int kb = 0; kb < 8; ++kb)
            if ((pm >> kb) & 1) {
                if (__any(fdirty(d[kb]))) nm |= 1u << kb;
            }
        if (!nm) return;
        pm = nm;
        __builtin_amdgcn_s_sleep(1);
        if (mode == 1 && !sys && ++tries == 16) { sys = true; PP = P + MOFF; }
        if (sys) {
#pragma unroll
            for (int kb = 0; kb < 8; ++kb)
                if ((pm >> kb) & 1) d[kb] = ld16p<true>(PP + kb * 512);
        } else {
#pragma unroll
            for (int kb = 0; kb < 8; ++kb)
                if ((pm >> kb) & 1) d[kb] = ld16p<false>(PP + kb * 512);
        }
    }
}

// ---------------- x [B,T,V] fp32 -> xT [T,B,V] bf16 ----------------
__global__ __launch_bounds__(256) void cvt_kernel(const float* __restrict__ x,
                                                  unsigned short* __restrict__ xT) {
    unsigned g = blockIdx.x * 256u + threadIdx.x;
    unsigned base = g * 8u;
    unsigned r = base >> 8;  // r = t*128 + b
    unsigned v = base & 255u;
    unsigned t = r >> 7, b = r & 127u;
    const float4* src = (const float4*)(x + ((size_t)b * Tt + t) * Vt + v);
    float4 f0 = src[0], f1 = src[1];
    union { unsigned short s[8]; int4 q; } o;
    o.s[0] = f2bf(f0.x); o.s[1] = f2bf(f0.y); o.s[2] = f2bf(f0.z); o.s[3] = f2bf(f0.w);
    o.s[4] = f2bf(f1.x); o.s[5] = f2bf(f1.y); o.s[6] = f2bf(f1.z); o.s[7] = f2bf(f1.w);
    *(int4*)(xT + (size_t)r * Vt + v) = o.q;
}

// ---------------- sentinel pre-fill (plain stores; dispatch-end flush) ------
__global__ __launch_bounds__(256) void fill_kernel(unsigned short* __restrict__ h) {
    size_t i = ((size_t)blockIdx.x * 256u + threadIdx.x) * 16u;  // shorts
    i32x4 s = (i32x4){0x7FFF7FFF, 0x7FFF7FFF, 0x7FFF7FFF, 0x7FFF7FFF};
    *(i32x4*)(h + i) = s;
    *(i32x4*)(h + i + 8) = s;
}

// ---------------- persistent dataflow recurrence: 128 WGs ----------------
__global__ __launch_bounds__(256) void rec_kernel(
    const float* __restrict__ Wih1, const float* __restrict__ Whh1,
    const float* __restrict__ bih1, const float* __restrict__ bhh1,
    const float* __restrict__ Wih2, const float* __restrict__ Whh2,
    const float* __restrict__ bih2, const float* __restrict__ bhh2,
    const unsigned short* __restrict__ xT,
    unsigned short* h1s, unsigned short* h2s, int mode) {
    const int bid = blockIdx.x;
    const int rgrp = bid & 7;       // batch group -> XCD
    const int lc = bid >> 3;        // 0..15
    const int layer = lc >> 3;
    const int cgrp = lc & 7;        // h-col group (32 cols)

    const float* Win = layer ? Wih2 : Wih1;
    const float* Whh = layer ? Whh2 : Whh1;
    const float* bi = layer ? bih2 : bih1;
    const float* bh = layer ? bhh2 : bhh1;

    // [matrix][wave][32 gate rows][256K + pad]; pad 266 -> row stride 133 dw
    // (odd-ish) => ds_read_b128 conflicts <=2-way (free, m136)
    __shared__ unsigned short sW[2][4][32][266];
    __shared__ unsigned short sH[16][32];

    const int tid = threadIdx.x;
    {   // stage both matrices: thread -> (row tid>>1, K-half tid&1)
        int row = tid >> 1, seg = (tid & 1) * 128;
        int wvs = row >> 5, lw = row & 31, grp = lw >> 3, loc = lw & 7;
        size_t grow = (size_t)(256 * grp + 32 * cgrp + 8 * wvs + loc) * Vt + seg;
        for (int m = 0; m < 2; ++m) {
            const float* src = (m ? Whh : Win) + grow;
            unsigned short* dst = &sW[m][wvs][lw][seg];
            for (int k = 0; k < 128; k += 4) {
                float4 f = *(const float4*)(src + k);
                dst[k + 0] = f2bf(f.x); dst[k + 1] = f2bf(f.y);
                dst[k + 2] = f2bf(f.z); dst[k + 3] = f2bf(f.w);
            }
        }
    }
    __syncthreads();  // only barrier: weights staged

    const int lane = tid & 63;
    const int wv = tid >> 6;
    const int q = lane >> 4;
    const int ln = lane & 15;

    float biasv[2];
#pragma unroll
    for (int nb = 0; nb < 2; ++nb) {
        int grp = nb * 2 + (ln >> 3);
        int grow = 256 * grp + 32 * cgrp + 8 * wv + (ln & 7);
        biasv[nb] = bi[grow] + bh[grow];
    }
    float cst[4] = {0.f, 0.f, 0.f, 0.f};

    const int hoff = rgrp * 4096 + ln * 32 + q * 8;          // consumer A-frag
    const int xoff = (16 * rgrp + ln) * 256 + q * 8;         // xT A-frag (L1)
    const int soff = rgrp * 4096 + cgrp * 512 +
                     (lane >> 1) * 32 + wv * 8 + (lane & 1) * 4;  // producer
    unsigned short* ob = layer ? h2s : h1s;

    if (layer == 0) {
        bf16x8 axc[8], axn[8], ah[8];
        {   // prologue: x[0] fragments
            const unsigned short* xp = xT + xoff;
#pragma unroll
            for (int kb = 0; kb < 8; ++kb) axc[kb] = *(const bf16x8*)(xp + kb * 32);
        }
        for (int t = 0; t < Tt; ++t) {
            f32x4 acc[2];
            acc[0] = (f32x4){biasv[0], biasv[0], biasv[0], biasv[0]};
            acc[1] = (f32x4){biasv[1], biasv[1], biasv[1], biasv[1]};

            const unsigned short* hP = h1s + (size_t)(t - 1) * TS + hoff;
            if (t > 0) {  // issue h1[t-1] poll loads (flight hides under x-GEMM)
                if (mode) ldset<false>(ah, hP); else ldset<true>(ah, hP);
            }
            if (t + 1 < Tt) {  // prefetch x[t+1] (consumed next iter, no wait)
                const unsigned short* xp = xT + (size_t)(t + 1) * TS + xoff;
#pragma unroll
                for (int kb = 0; kb < 8; ++kb) axn[kb] = *(const bf16x8*)(xp + kb * 32);
            }
            // x-GEMM on resident regs -- zero memory wait
#pragma unroll
            for (int kb = 0; kb < 8; ++kb) {
                bf16x8 b0 = *(const bf16x8*)&sW[0][wv][ln][kb * 32 + q * 8];
                bf16x8 b1 = *(const bf16x8*)&sW[0][wv][16 + ln][kb * 32 + q * 8];
                acc[0] = MFMA(axc[kb], b0, acc[0]);
                acc[1] = MFMA(axc[kb], b1, acc[1]);
            }
            if (t > 0) {
                pollset(ah, hP, mode);
#pragma unroll
                for (int kb = 0; kb < 8; ++kb) {
                    bf16x8 b0 = *(const bf16x8*)&sW[1][wv][ln][kb * 32 + q * 8];
                    bf16x8 b1 = *(const bf16x8*)&sW[1][wv][16 + ln][kb * 32 + q * 8];
                    acc[0] = MFMA(ah[kb], b0, acc[0]);
                    acc[1] = MFMA(ah[kb], b1, acc[1]);
                }
            }
            // cell: lane ln holds (i|f) in acc[0], (g|o) in acc[1]
#pragma unroll
            for (int r = 0; r < 4; ++r) {
                float a0 = acc[0][r], a1 = acc[1][r];
                float b0 = __shfl_xor(a0, 8), b1 = __shfl_xor(a1, 8);
                float iv, fv, gv, ov;
                if (ln < 8) { iv = a0; fv = b0; gv = a1; ov = b1; }
                else        { iv = b0; fv = a0; gv = b1; ov = a1; }
                float ii = sigm(iv), ff = sigm(fv), gg = tanh_f(gv), oo = sigm(ov);
                float cc = ff * cst[r] + ii * gg;
                cst[r] = cc;
                float hh = oo * tanh_f(cc);
                if (ln < 8) sH[q * 4 + r][8 * wv + ln] = f2bf(hh);
            }
            if (lane < 32) {  // coalesced 256B wave store of its 16x8 slice
                unsigned long long hv =
                    *(const unsigned long long*)&sH[lane >> 1][8 * wv + (lane & 1) * 4];
                unsigned short* dst = ob + (size_t)t * TS + soff;
                if (mode) {
                    asm volatile("global_store_dwordx2 %0, %1, off sc0" ::"v"(dst),
                                 "v"(hv) : "memory");
                    asm volatile("global_store_dwordx2 %0, %1, off sc0 sc1" ::"v"(
                                     dst + MOFF), "v"(hv) : "memory");
                } else {
                    asm volatile("global_store_dwordx2 %0, %1, off sc0 sc1" ::"v"(dst),
                                 "v"(hv) : "memory");
                }
            }
#pragma unroll
            for (int kb = 0; kb < 8; ++kb) axc[kb] = axn[kb];
        }
    } else {
        bf16x8 ai[8], ah[8];
        for (int t = 0; t < Tt; ++t) {
            f32x4 acc[2];
            acc[0] = (f32x4){biasv[0], biasv[0], biasv[0], biasv[0]};
            acc[1] = (f32x4){biasv[1], biasv[1], biasv[1], biasv[1]};

            const unsigned short* hP1 = h1s + (size_t)t * TS + hoff;
            const unsigned short* hP2 = h2s + (size_t)(t - 1) * TS + hoff;
            if (mode) ldset<false>(ai, hP1); else ldset<true>(ai, hP1);
            if (t > 0) {
                if (mode) ldset<false>(ah, hP2); else ldset<true>(ah, hP2);
                // own h2 self-loop first; ai stays in flight meanwhile
                pollset(ah, hP2, mode);
#pragma unroll
                for (int kb = 0; kb < 8; ++kb) {
                    bf16x8 b0 = *(const bf16x8*)&sW[1][wv][ln][kb * 32 + q * 8];
                    bf16x8 b1 = *(const bf16x8*)&sW[1][wv][16 + ln][kb * 32 + q * 8];
                    acc[0] = MFMA(ah[kb], b0, acc[0]);
                    acc[1] = MFMA(ah[kb], b1, acc[1]);
                }
            }
            pollset(ai, hP1, mode);  // h1[t] usually clean by now (L1 leads)
#pragma unroll
            for (int kb = 0; kb < 8; ++kb) {
                bf16x8 b0 = *(const bf16x8*)&sW[0][wv][ln][kb * 32 + q * 8];
                bf16x8 b1 = *(const bf16x8*)&sW[0][wv][16 + ln][kb * 32 + q * 8];
                acc[0] = MFMA(ai[kb], b0, acc[0]);
                acc[1] = MFMA(ai[kb], b1, acc[1]);
            }
#pragma unroll
            for (int r = 0; r < 4; ++r) {
                float a0 = acc[0][r], a1 = acc[1][r];
                float b0 = __shfl_xor(a0, 8), b1 = __shfl_xor(a1, 8);
                float iv, fv, gv, ov;
                if (ln < 8) { iv = a0; fv = b0; gv = a1; ov = b1; }
                else        { iv = b0; fv = a0; gv = b1; ov = a1; }
                float ii = sigm(iv), ff = sigm(fv), gg = tanh_f(gv), oo = sigm(ov);
                float cc = ff * cst[r] + ii * gg;
                cst[r] = cc;
                float hh = oo * tanh_f(cc);
                if (ln < 8) sH[q * 4 + r][8 * wv + ln] = f2bf(hh);
            }
            if (lane < 32) {
                unsigned long long hv =
                    *(const unsigned long long*)&sH[lane >> 1][8 * wv + (lane & 1) * 4];
                unsigned short* dst = ob + (size_t)t * TS + soff;
                if (mode) {
                    asm volatile("global_store_dwordx2 %0, %1, off sc0" ::"v"(dst),
                                 "v"(hv) : "memory");
                    asm volatile("global_store_dwordx2 %0, %1, off sc0 sc1" ::"v"(
                                     dst + MOFF), "v"(hv) : "memory");
                } else {
                    asm volatile("global_store_dwordx2 %0, %1, off sc0 sc1" ::"v"(dst),
                                 "v"(hv) : "memory");
                }
            }
        }
    }
}

// ---------------- out[b,t,:] = h2s_tiled[t] @ w_n^T + fc_b ----------------
__global__ __launch_bounds__(256) void fc_kernel(const unsigned short* __restrict__ h2s,
                                                 const float* __restrict__ fcw,
                                                 const float* __restrict__ fcb,
                                                 float* __restrict__ out) {
    const int bid = blockIdx.x;
    const int rb = bid >> 2;  // t
    const int c0 = (bid & 3) * 64;
    __shared__ unsigned short sWf[64][264];
    __shared__ float sInv[64];
    const int tid = threadIdx.x;
    if (tid < 64) {
        const float* wr = fcw + (size_t)(c0 + tid) * 256;
        float s = 0.f;
        for (int k = 0; k < 256; k += 4) {
            float4 f = *(const float4*)(wr + k);
            s += f.x * f.x + f.y * f.y + f.z * f.z + f.w * f.w;
        }
        sInv[tid] = rsqrtf(s);
    }
    __syncthreads();
    {
        int lr = tid & 63, seg = tid >> 6;
        float inv = sInv[lr];
        const float* wr = fcw + (size_t)(c0 + lr) * 256 + seg * 64;
        unsigned short* dst = &sWf[lr][seg * 64];
        for (int k = 0; k < 64; k += 4) {
            float4 f = *(const float4*)(wr + k);
            dst[k + 0] = f2bf(f.x * inv); dst[k + 1] = f2bf(f.y * inv);
            dst[k + 2] = f2bf(f.z * inv); dst[k + 3] = f2bf(f.w * inv);
        }
    }
    __syncthreads();
    const int lane = tid & 63, w = tid >> 6, q = lane >> 4, ln = lane & 15;
    f32x4 acc[2][4];
    for (int rk = 0; rk < 2; ++rk)
        for (int nb = 0; nb < 4; ++nb) {
            float bv = fcb[c0 + nb * 16 + ln];
            acc[rk][nb] = (f32x4){bv, bv, bv, bv};
        }
    // tiled h2: [rgrp][cgrp][16][32]; wave w covers rgrps {2w, 2w+1}
    const unsigned short* P0 =
        h2s + (size_t)rb * TS + (2 * w) * 4096 + ln * 32 + q * 8;
    const unsigned short* P1 = P0 + 4096;
    for (int kb = 0; kb < 8; ++kb) {
        bf16x8 a0 = *(const bf16x8*)(P0 + kb * 512);
        bf16x8 a1 = *(const bf16x8*)(P1 + kb * 512);
        for (int nb = 0; nb < 4; ++nb) {
            bf16x8 b = *(const bf16x8*)&sWf[nb * 16 + ln][kb * 32 + q * 8];
            acc[0][nb] = MFMA(a0, b, acc[0][nb]);
            acc[1][nb] = MFMA(a1, b, acc[1][nb]);
        }
    }
    for (int rk = 0; rk < 2; ++rk)
        for (int nb = 0; nb < 4; ++nb)
            for (int r = 0; r < 4; ++r) {
                int bb = 32 * w + rk * 16 + q * 4 + r;
                int o = c0 + nb * 16 + ln;
                out[((size_t)bb * Tt + rb) * 256 + o] = acc[rk][nb][r];
            }
}

extern "C" void kernel_launch(void* const* d_in, const int* in_sizes, int n_in,
                              void* d_out, int out_size, void* d_ws, size_t ws_size,
                              hipStream_t stream) {
    const float* x    = (const float*)d_in[0];
    const float* Wih1 = (const float*)d_in[1];
    const float* Whh1 = (const float*)d_in[2];
    const float* bih1 = (const float*)d_in[3];
    const float* bhh1 = (const float*)d_in[4];
    const float* Wih2 = (const float*)d_in[5];
    const float* Whh2 = (const float*)d_in[6];
    const float* bih2 = (const float*)d_in[7];
    const float* bhh2 = (const float*)d_in[8];
    const float* fcw  = (const float*)d_in[9];
    const float* fcb  = (const float*)d_in[10];

    char* ws = (char*)d_ws;
    unsigned short* xT  = (unsigned short*)ws;                  // 64MB
    unsigned short* h1s = xT + (size_t)Tt * TS;                 // 64MB (local)
    unsigned short* h2s = h1s + (size_t)Tt * TS;                // 64MB (local)
    // mirrors (mode=1): h1s+MOFF (=ws+192MB), h2s+MOFF (=ws+256MB)

    int mode = (ws_size >= (size_t)320 * 1024 * 1024) ? 1 : 0;

    // sentinel-fill h1+h2 (+mirrors in mode 1): contiguous from h1s
    fill_kernel<<<(mode ? 32768 : 16384), 256, 0, stream>>>(h1s);
    cvt_kernel<<<16384, 256, 0, stream>>>(x, xT);
    rec_kernel<<<128, 256, 0, stream>>>(Wih1, Whh1, bih1, bhh1,
                                        Wih2, Whh2, bih2, bhh2,
                                        xT, h1s, h2s, mode);
    fc_kernel<<<4096, 256, 0, stream>>>(h2s, fcw, fcb, (float*)d_out);
}

// Round 7
// 8221.997 us; speedup vs baseline: 1.5705x; 1.5705x over previous
//
#include <hip/hip_runtime.h>
#include <stdint.h>

#define Tt 1024
#define Bt 128
#define Vt 256
#define TS 32768  // shorts per t-slice

typedef __attribute__((ext_vector_type(8))) short bf16x8;
typedef __attribute__((ext_vector_type(4))) float f32x4;
typedef __attribute__((ext_vector_type(4))) int i32x4;

#define MFMA(a, b, c) __builtin_amdgcn_mfma_f32_16x16x32_bf16(a, b, c, 0, 0, 0)
#define SENT 0x7FFF  // bf16 NaN: unreachable from f2bf(finite h)

// ---- structure -------------------------------------------------------------
// 256 WGs launched (137KB LDS => exactly 1 WG/CU => all resident, 32/XCD).
// Each WG reads its XCD via s_getreg(HW_REG_XCC_ID) and claims a slot from a
// per-XCD pool: slots 0..15 = (layer 0..1) x (cgrp 0..7); surplus WGs exit.
// XCD x owns batch-group bg=x (rows [16x,16x+16)). All producers+consumers of
// a bg share one XCD, so h exchange = sc0 stores/loads through that XCD's L2.
// h layout row-major [t][b][v] (bg block = rows 16bg..16bg+16). Mirror copies
// (MALL, sc0 sc1) live in d_out; consumers fall back after 64 failed rounds.

__device__ __forceinline__ unsigned short f2bf(float f) {
    unsigned u = __builtin_bit_cast(unsigned, f);
    u += 0x7fffu + ((u >> 16) & 1u);
    return (unsigned short)(u >> 16);
}
__device__ __forceinline__ float sigm(float x) {
    return __builtin_amdgcn_rcpf(1.f + __expf(-x));
}
__device__ __forceinline__ float tanh_f(float x) {
    float e = __expf(-2.f * fabsf(x));
    float t = (1.f - e) * __builtin_amdgcn_rcpf(1.f + e);
    return copysignf(t, x);
}

// coherent 16B load: SYS=false -> sc0 (XCD L2 scope); SYS=true -> sc0 sc1 (MALL)
template <int OFF, bool SYS>
__device__ __forceinline__ bf16x8 ld16(const unsigned short* p) {
    bf16x8 d;
    if constexpr (SYS)
        asm volatile("global_load_dwordx4 %0, %1, off offset:%c2 sc0 sc1"
                     : "=v"(d) : "v"(p), "i"(OFF));
    else
        asm volatile("global_load_dwordx4 %0, %1, off offset:%c2 sc0"
                     : "=v"(d) : "v"(p), "i"(OFF));
    return d;
}
template <bool SYS>
__device__ __forceinline__ void ld8(bf16x8 (&d)[8], const unsigned short* P) {
    d[0] = ld16<0, SYS>(P);   d[1] = ld16<64, SYS>(P);
    d[2] = ld16<128, SYS>(P); d[3] = ld16<192, SYS>(P);
    d[4] = ld16<256, SYS>(P); d[5] = ld16<320, SYS>(P);
    d[6] = ld16<384, SYS>(P); d[7] = ld16<448, SYS>(P);
}
__device__ __forceinline__ void vm_drain() {
    asm volatile("s_waitcnt vmcnt(0)" ::: "memory");
    __builtin_amdgcn_sched_barrier(0);  // rule #18
}
__device__ __forceinline__ int fdirty(bf16x8 f) {
    i32x4 d = __builtin_bit_cast(i32x4, f);
    return ((d.x & 0xFFFF) == SENT) | ((d.z & 0xFFFF) == SENT);
}

// ---------------- x [B,T,V] fp32 -> xT [T,B,V] bf16 ----------------
__global__ __launch_bounds__(256) void cvt_kernel(const float* __restrict__ x,
                                                  unsigned short* __restrict__ xT) {
    unsigned g = blockIdx.x * 256u + threadIdx.x;
    unsigned base = g * 8u;
    unsigned r = base >> 8;  // r = t*128 + b
    unsigned v = base & 255u;
    unsigned t = r >> 7, b = r & 127u;
    const float4* src = (const float4*)(x + ((size_t)b * Tt + t) * Vt + v);
    float4 f0 = src[0], f1 = src[1];
    union { unsigned short s[8]; int4 q; } o;
    o.s[0] = f2bf(f0.x); o.s[1] = f2bf(f0.y); o.s[2] = f2bf(f0.z); o.s[3] = f2bf(f0.w);
    o.s[4] = f2bf(f1.x); o.s[5] = f2bf(f1.y); o.s[6] = f2bf(f1.z); o.s[7] = f2bf(f1.w);
    *(int4*)(xT + (size_t)r * Vt + v) = o.q;
}

// ---------------- sentinel pre-fill (plain stores; dispatch-end flush) ------
__global__ __launch_bounds__(256) void fill_kernel(unsigned short* __restrict__ h) {
    size_t i = ((size_t)blockIdx.x * 256u + threadIdx.x) * 16u;  // shorts
    i32x4 s = (i32x4){0x7FFF7FFF, 0x7FFF7FFF, 0x7FFF7FFF, 0x7FFF7FFF};
    *(i32x4*)(h + i) = s;
    *(i32x4*)(h + i + 8) = s;
}

// ---------------- persistent dataflow recurrence ----------------
__global__ __launch_bounds__(256) void rec_kernel(
    const float* __restrict__ Wih1, const float* __restrict__ Whh1,
    const float* __restrict__ bih1, const float* __restrict__ bhh1,
    const float* __restrict__ Wih2, const float* __restrict__ Whh2,
    const float* __restrict__ bih2, const float* __restrict__ bhh2,
    const unsigned short* __restrict__ xT,
    unsigned short* h1s, unsigned short* h2s,
    unsigned short* mir1, unsigned short* mir2, unsigned int* pool) {
    // sW: per wave-block 32 gate rows (i0-7|f0-7|g0-7|o0-7) x K=256; pad 264
    // -> row stride 132 dw == 4 mod 32 => balanced banks on b128 reads
    __shared__ unsigned short sW[2][4][32][264];  // 135KB
    __shared__ unsigned short sH[4][16][8];
    __shared__ int sRole;

    const int tid = threadIdx.x;
    if (tid == 0) {
        unsigned xcd;
        asm volatile("s_getreg_b32 %0, hwreg(HW_REG_XCC_ID)" : "=s"(xcd));
        xcd &= 7u;
        unsigned slot = __hip_atomic_fetch_add(&pool[xcd], 1u, __ATOMIC_RELAXED,
                                               __HIP_MEMORY_SCOPE_AGENT);
        sRole = (slot < 16u) ? (int)(xcd * 16u + slot) : -1;
    }
    __syncthreads();
    const int role = sRole;
    if (role < 0) return;  // surplus WG
    const int bg = role >> 4;         // batch group == this XCD
    const int layer = (role >> 3) & 1;
    const int cgrp = role & 7;        // 32 h-cols [32cgrp, 32cgrp+32)

    const float* Win = layer ? Wih2 : Wih1;
    const float* Whh = layer ? Whh2 : Whh1;
    const float* bi = layer ? bih2 : bih1;
    const float* bh = layer ? bhh2 : bhh1;

    {   // stage weights: thread -> (WG row tid>>1 of 128, K-half tid&1)
        int row = tid >> 1, seg = (tid & 1) * 128;
        int wvs = row >> 5, lw = row & 31, grp = lw >> 3, loc = lw & 7;
        size_t grow = (size_t)(256 * grp + 32 * cgrp + 8 * wvs + loc) * Vt + seg;
        for (int m = 0; m < 2; ++m) {
            const float* src = (m ? Whh : Win) + grow;
            unsigned short* dst = &sW[m][wvs][lw][seg];
            for (int k = 0; k < 128; k += 4) {
                float4 f = *(const float4*)(src + k);
                dst[k + 0] = f2bf(f.x); dst[k + 1] = f2bf(f.y);
                dst[k + 2] = f2bf(f.z); dst[k + 3] = f2bf(f.w);
            }
        }
    }
    __syncthreads();

    const int lane = tid & 63;
    const int wv = tid >> 6;
    const int q = lane >> 4;
    const int ln = lane & 15;
    const int hc0g = 32 * cgrp + 8 * wv;  // this wave's 8 h-cols

    float biasv[2];
#pragma unroll
    for (int nb = 0; nb < 2; ++nb) {
        int grp = nb * 2 + (ln >> 3);
        biasv[nb] = bi[256 * grp + hc0g + (ln & 7)] + bh[256 * grp + hc0g + (ln & 7)];
    }
    float cst[4] = {0.f, 0.f, 0.f, 0.f};

    // consumer A-frag base: row 16bg+ln, K-cols q*8 (+kb*32); row-major
    const int hoff = (16 * bg + ln) * 256 + q * 8;
    // producer store: lane L<32 -> row 16bg+(L>>1), cols hc0g+(L&1)*4 (8B)
    const size_t soff = (size_t)(16 * bg + (lane >> 1)) * 256 + hc0g + (lane & 1) * 4;

    unsigned short* ob = layer ? h2s : h1s;
    unsigned short* obm = layer ? mir2 : mir1;
    bool gsys = false;  // permanent mirror fallback once triggered

    if (layer == 0) {
        bf16x8 axc[8], axn[8], ah[8];
#pragma unroll
        for (int kb = 0; kb < 8; ++kb) axc[kb] = *(const bf16x8*)(xT + hoff + kb * 32);
        for (int t = 0; t < Tt; ++t) {
            f32x4 acc[2];
            acc[0] = (f32x4){biasv[0], biasv[0], biasv[0], biasv[0]};
            acc[1] = (f32x4){biasv[1], biasv[1], biasv[1], biasv[1]};

            const unsigned short* hP = h1s + (size_t)(t - 1) * TS + hoff;
            const unsigned short* hM = mir1 + (size_t)(t - 1) * TS + hoff;
            if (t > 0) {
                if (gsys) ld8<true>(ah, hM); else ld8<false>(ah, hP);
                int tries = 0;
                for (;;) {
                    vm_drain();
                    int d = 0;
#pragma unroll
                    for (int kb = 0; kb < 8; ++kb) d |= fdirty(ah[kb]);
                    if (!__any(d)) break;
                    __builtin_amdgcn_s_sleep(1);
                    if (!gsys && ++tries == 64) gsys = true;
                    if (gsys) ld8<true>(ah, hM); else ld8<false>(ah, hP);
                }
            }
            if (t + 1 < Tt) {  // x[t+1] reg prefetch (plain cached loads)
                const unsigned short* xp = xT + (size_t)(t + 1) * TS + hoff;
#pragma unroll
                for (int kb = 0; kb < 8; ++kb) axn[kb] = *(const bf16x8*)(xp + kb * 32);
            }
#pragma unroll
            for (int kb = 0; kb < 8; ++kb) {
                bf16x8 b0 = *(const bf16x8*)&sW[0][wv][ln][kb * 32 + q * 8];
                bf16x8 b1 = *(const bf16x8*)&sW[0][wv][16 + ln][kb * 32 + q * 8];
                acc[0] = MFMA(axc[kb], b0, acc[0]);
                acc[1] = MFMA(axc[kb], b1, acc[1]);
            }
            if (t > 0) {
#pragma unroll
                for (int kb = 0; kb < 8; ++kb) {
                    bf16x8 b0 = *(const bf16x8*)&sW[1][wv][ln][kb * 32 + q * 8];
                    bf16x8 b1 = *(const bf16x8*)&sW[1][wv][16 + ln][kb * 32 + q * 8];
                    acc[0] = MFMA(ah[kb], b0, acc[0]);
                    acc[1] = MFMA(ah[kb], b1, acc[1]);
                }
            }
            // cell: lane ln holds (i|f) in acc[0], (g|o) in acc[1]; 16 rows
#pragma unroll
            for (int r = 0; r < 4; ++r) {
                float a0 = acc[0][r], a1 = acc[1][r];
                float b0 = __shfl_xor(a0, 8), b1 = __shfl_xor(a1, 8);
                float iv, fv, gv, ov;
                if (ln < 8) { iv = a0; fv = b0; gv = a1; ov = b1; }
                else        { iv = b0; fv = a0; gv = b1; ov = a1; }
                float ii = sigm(iv), ff = sigm(fv), gg = tanh_f(gv), oo = sigm(ov);
                float cc = ff * cst[r] + ii * gg;
                cst[r] = cc;
                float hh = oo * tanh_f(cc);
                if (ln < 8) sH[wv][q * 4 + r][ln] = f2bf(hh);
            }
            asm volatile("s_waitcnt lgkmcnt(0)" ::: "memory");
            __builtin_amdgcn_sched_barrier(0);
            if (lane < 32) {
                unsigned long long hv =
                    *(const unsigned long long*)&sH[wv][lane >> 1][(lane & 1) * 4];
                unsigned short* dl = ob + (size_t)t * TS + soff;
                unsigned short* dm = obm + (size_t)t * TS + soff;
                asm volatile("global_store_dwordx2 %0, %1, off sc0" ::"v"(dl), "v"(hv)
                             : "memory");
                asm volatile("global_store_dwordx2 %0, %1, off sc0 sc1" ::"v"(dm),
                             "v"(hv) : "memory");
            }
#pragma unroll
            for (int kb = 0; kb < 8; ++kb) axc[kb] = axn[kb];
        }
    } else {
        bf16x8 ai[8], ah[8];
        for (int t = 0; t < Tt; ++t) {
            f32x4 acc[2];
            acc[0] = (f32x4){biasv[0], biasv[0], biasv[0], biasv[0]};
            acc[1] = (f32x4){biasv[1], biasv[1], biasv[1], biasv[1]};

            const unsigned short* P1 = h1s + (size_t)t * TS + hoff;
            const unsigned short* M1 = mir1 + (size_t)t * TS + hoff;
            const unsigned short* P2 = h2s + (size_t)(t - 1) * TS + hoff;
            const unsigned short* M2 = mir2 + (size_t)(t - 1) * TS + hoff;
            if (gsys) ld8<true>(ai, M1); else ld8<false>(ai, P1);
            if (t > 0) { if (gsys) ld8<true>(ah, M2); else ld8<false>(ah, P2); }
            unsigned need = (t > 0) ? 3u : 1u;
            int tries = 0;
            for (;;) {
                vm_drain();
                unsigned nm = 0;
                if (need & 1) {
                    int d = 0;
#pragma unroll
                    for (int kb = 0; kb < 8; ++kb) d |= fdirty(ai[kb]);
                    if (__any(d)) nm |= 1u;
                }
                if (need & 2) {
                    int d = 0;
#pragma unroll
                    for (int kb = 0; kb < 8; ++kb) d |= fdirty(ah[kb]);
                    if (__any(d)) nm |= 2u;
                }
                if (!nm) break;
                need = nm;
                __builtin_amdgcn_s_sleep(1);
                if (!gsys && ++tries == 64) gsys = true;
                if (nm & 1) { if (gsys) ld8<true>(ai, M1); else ld8<false>(ai, P1); }
                if (nm & 2) { if (gsys) ld8<true>(ah, M2); else ld8<false>(ah, P2); }
            }
#pragma unroll
            for (int kb = 0; kb < 8; ++kb) {
                bf16x8 b0 = *(const bf16x8*)&sW[0][wv][ln][kb * 32 + q * 8];
                bf16x8 b1 = *(const bf16x8*)&sW[0][wv][16 + ln][kb * 32 + q * 8];
                acc[0] = MFMA(ai[kb], b0, acc[0]);
                acc[1] = MFMA(ai[kb], b1, acc[1]);
            }
            if (t > 0) {
#pragma unroll
                for (int kb = 0; kb < 8; ++kb) {
                    bf16x8 b0 = *(const bf16x8*)&sW[1][wv][ln][kb * 32 + q * 8];
                    bf16x8 b1 = *(const bf16x8*)&sW[1][wv][16 + ln][kb * 32 + q * 8];
                    acc[0] = MFMA(ah[kb], b0, acc[0]);
                    acc[1] = MFMA(ah[kb], b1, acc[1]);
                }
            }
#pragma unroll
            for (int r = 0; r < 4; ++r) {
                float a0 = acc[0][r], a1 = acc[1][r];
                float b0 = __shfl_xor(a0, 8), b1 = __shfl_xor(a1, 8);
                float iv, fv, gv, ov;
                if (ln < 8) { iv = a0; fv = b0; gv = a1; ov = b1; }
                else        { iv = b0; fv = a0; gv = b1; ov = a1; }
                float ii = sigm(iv), ff = sigm(fv), gg = tanh_f(gv), oo = sigm(ov);
                float cc = ff * cst[r] + ii * gg;
                cst[r] = cc;
                float hh = oo * tanh_f(cc);
                if (ln < 8) sH[wv][q * 4 + r][ln] = f2bf(hh);
            }
            asm volatile("s_waitcnt lgkmcnt(0)" ::: "memory");
            __builtin_amdgcn_sched_barrier(0);
            if (lane < 32) {
                unsigned long long hv =
                    *(const unsigned long long*)&sH[wv][lane >> 1][(lane & 1) * 4];
                unsigned short* dl = ob + (size_t)t * TS + soff;
                unsigned short* dm = obm + (size_t)t * TS + soff;
                asm volatile("global_store_dwordx2 %0, %1, off sc0" ::"v"(dl), "v"(hv)
                             : "memory");
                asm volatile("global_store_dwordx2 %0, %1, off sc0 sc1" ::"v"(dm),
                             "v"(hv) : "memory");
            }
        }
    }
}

// ---------------- out[b,t,:] = h2s[t,b,:] @ w_n^T + fc_b ----------------
__global__ __launch_bounds__(256) void fc_kernel(const unsigned short* __restrict__ h2s,
                                                 const float* __restrict__ fcw,
                                                 const float* __restrict__ fcb,
                                                 float* __restrict__ out) {
    const int bid = blockIdx.x;
    const int rb = bid >> 2;  // t
    const int c0 = (bid & 3) * 64;
    __shared__ unsigned short sWf[64][264];
    __shared__ float sInv[64];
    const int tid = threadIdx.x;
    if (tid < 64) {
        const float* wr = fcw + (size_t)(c0 + tid) * 256;
        float s = 0.f;
        for (int k = 0; k < 256; k += 4) {
            float4 f = *(const float4*)(wr + k);
            s += f.x * f.x + f.y * f.y + f.z * f.z + f.w * f.w;
        }
        sInv[tid] = rsqrtf(s);
    }
    __syncthreads();
    {
        int lr = tid & 63, seg = tid >> 6;
        float inv = sInv[lr];
        const float* wr = fcw + (size_t)(c0 + lr) * 256 + seg * 64;
        unsigned short* dst = &sWf[lr][seg * 64];
        for (int k = 0; k < 64; k += 4) {
            float4 f = *(const float4*)(wr + k);
            dst[k + 0] = f2bf(f.x * inv); dst[k + 1] = f2bf(f.y * inv);
            dst[k + 2] = f2bf(f.z * inv); dst[k + 3] = f2bf(f.w * inv);
        }
    }
    __syncthreads();
    const int lane = tid & 63, w = tid >> 6, q = lane >> 4, ln = lane & 15;
    f32x4 acc[2][4];
    for (int rk = 0; rk < 2; ++rk)
        for (int nb = 0; nb < 4; ++nb) {
            float bv = fcb[c0 + nb * 16 + ln];
            acc[rk][nb] = (f32x4){bv, bv, bv, bv};
        }
    const unsigned short* ap = h2s + (size_t)rb * TS;
    for (int kb = 0; kb < 8; ++kb) {
        bf16x8 a0 = *(const bf16x8*)(ap + (32 * w + ln) * 256 + kb * 32 + q * 8);
        bf16x8 a1 = *(const bf16x8*)(ap + (32 * w + 16 + ln) * 256 + kb * 32 + q * 8);
        for (int nb = 0; nb < 4; ++nb) {
            bf16x8 b = *(const bf16x8*)&sWf[nb * 16 + ln][kb * 32 + q * 8];
            acc[0][nb] = MFMA(a0, b, acc[0][nb]);
            acc[1][nb] = MFMA(a1, b, acc[1][nb]);
        }
    }
    for (int rk = 0; rk < 2; ++rk)
        for (int nb = 0; nb < 4; ++nb)
            for (int r = 0; r < 4; ++r) {
                int bb = 32 * w + rk * 16 + q * 4 + r;
                int o = c0 + nb * 16 + ln;
                out[((size_t)bb * Tt + rb) * 256 + o] = acc[rk][nb][r];
            }
}

extern "C" void kernel_launch(void* const* d_in, const int* in_sizes, int n_in,
                              void* d_out, int out_size, void* d_ws, size_t ws_size,
                              hipStream_t stream) {
    const float* x    = (const float*)d_in[0];
    const float* Wih1 = (const float*)d_in[1];
    const float* Whh1 = (const float*)d_in[2];
    const float* bih1 = (const float*)d_in[3];
    const float* bhh1 = (const float*)d_in[4];
    const float* Wih2 = (const float*)d_in[5];
    const float* Whh2 = (const float*)d_in[6];
    const float* bih2 = (const float*)d_in[7];
    const float* bhh2 = (const float*)d_in[8];
    const float* fcw  = (const float*)d_in[9];
    const float* fcb  = (const float*)d_in[10];

    char* ws = (char*)d_ws;
    unsigned int* pool = (unsigned int*)ws;                    // 16KB header
    unsigned short* xT  = (unsigned short*)(ws + 16384);       // 64MB
    unsigned short* h1s = xT + (size_t)Tt * TS;                // 64MB
    unsigned short* h2s = h1s + (size_t)Tt * TS;               // 64MB
    // mirrors live in d_out (128MB = exactly 2x64MB); fc overwrites it later
    unsigned short* mir1 = (unsigned short*)d_out;
    unsigned short* mir2 = mir1 + (size_t)Tt * TS;

    hipMemsetAsync(ws, 0, 16384, stream);
    fill_kernel<<<16384, 256, 0, stream>>>(h1s);   // h1s+h2s (contiguous 128MB)
    fill_kernel<<<16384, 256, 0, stream>>>(mir1);  // mirrors (contiguous 128MB)
    cvt_kernel<<<16384, 256, 0, stream>>>(x, xT);
    rec_kernel<<<256, 256, 0, stream>>>(Wih1, Whh1, bih1, bhh1,
                                        Wih2, Whh2, bih2, bhh2,
                                        xT, h1s, h2s, mir1, mir2, pool);
    fc_kernel<<<4096, 256, 0, stream>>>(h2s, fcw, fcb, (float*)d_out);
}

// Round 9
// 3106.740 us; speedup vs baseline: 4.1564x; 2.6465x over previous
//
#include <hip/hip_runtime.h>
#include <stdint.h>

#define Tt 1024
#define Bt 128
#define Vt 256
#define TS 32768  // shorts per t-slice

typedef __attribute__((ext_vector_type(8))) short bf16x8;
typedef __attribute__((ext_vector_type(4))) float f32x4;
typedef __attribute__((ext_vector_type(4))) int i32x4;

#define MFMA(a, b, c) __builtin_amdgcn_mfma_f32_16x16x32_bf16(a, b, c, 0, 0, 0)
#define SENT 0x7FFF  // bf16 NaN: unreachable from f2bf(finite h in (-1,1))

// ---- geometry ---------------------------------------------------------------
// Per layer 64 WGs = 8 bgrp (16 batch rows, M=16) x 8 cgrp (32 h-cols = 128
// gate rows). WG holds BOTH W_ih and W_hh slices in LDS (132KB). Waves split
// by GATE TYPE (wave wv computes gate wv for all 32 cols); gates exchanged
// intra-WG via LDS; h tile (16x32 = 1KB) stored by wave 0 as ONE
// global_store_dwordx4 across 64 lanes -> consumer fan-in = 8 single-store
// tiles (was 32 scattered wave-stores), 8 poll loads/wave (was 16).
// h slice layout: [bgrp(8)][cgrp(8)][row(16)][col(32)] shorts;
//   consumer frag (kb,q,ln) = tile kb, 16B at ln*32+q*8 -- exactly one
//   producer lane-store -> sentinel-atomic.

__device__ __forceinline__ unsigned short f2bf(float f) {
    unsigned u = __builtin_bit_cast(unsigned, f);
    u += 0x7fffu + ((u >> 16) & 1u);
    return (unsigned short)(u >> 16);
}
__device__ __forceinline__ float sigm(float x) {
    return __builtin_amdgcn_rcpf(1.f + __expf(-x));
}
__device__ __forceinline__ float tanh_f(float x) {
    float e = __expf(-2.f * fabsf(x));
    float t = (1.f - e) * __builtin_amdgcn_rcpf(1.f + e);
    return copysignf(t, x);
}

// agent-coherent 16B load (sc0 sc1: MALL path -- the only coherent cross-CU
// path on gfx950, per R7). No wait attached; batch then drain once.
// NOTE: global offset: immediate is 13-bit SIGNED (max +4095) -> keep <=3072
// and use a second base pointer for the upper tiles.
template <int OFF>
__device__ __forceinline__ bf16x8 ldcc(const unsigned short* p) {
    bf16x8 d;
    asm volatile("global_load_dwordx4 %0, %1, off offset:%c2 sc0 sc1"
                 : "=v"(d) : "v"(p), "i"(OFF));
    return d;
}
// 8 A-frags: tile kb at +kb*1024 bytes; second base at +4096B (2048 shorts)
#define LD8T(d, P)                                        \
    do {                                                  \
        const unsigned short* _p2 = (P) + 2048;           \
        d[0] = ldcc<0>(P);      d[1] = ldcc<1024>(P);     \
        d[2] = ldcc<2048>(P);   d[3] = ldcc<3072>(P);     \
        d[4] = ldcc<0>(_p2);    d[5] = ldcc<1024>(_p2);   \
        d[6] = ldcc<2048>(_p2); d[7] = ldcc<3072>(_p2);   \
    } while (0)

__device__ __forceinline__ void vm_drain() {
    asm volatile("s_waitcnt vmcnt(0)" ::: "memory");
    __builtin_amdgcn_sched_barrier(0);  // rule #18
}
__device__ __forceinline__ int fdirty(bf16x8 f) {
    i32x4 d = __builtin_bit_cast(i32x4, f);
    return ((d.x & 0xFFFF) == SENT) | ((d.z & 0xFFFF) == SENT);
}

// ---------------- x [B,T,V] fp32 -> xT [T,B,V] bf16 ----------------
__global__ __launch_bounds__(256) void cvt_kernel(const float* __restrict__ x,
                                                  unsigned short* __restrict__ xT) {
    unsigned g = blockIdx.x * 256u + threadIdx.x;
    unsigned base = g * 8u;
    unsigned r = base >> 8;  // r = t*128 + b
    unsigned v = base & 255u;
    unsigned t = r >> 7, b = r & 127u;
    const float4* src = (const float4*)(x + ((size_t)b * Tt + t) * Vt + v);
    float4 f0 = src[0], f1 = src[1];
    union { unsigned short s[8]; int4 q; } o;
    o.s[0] = f2bf(f0.x); o.s[1] = f2bf(f0.y); o.s[2] = f2bf(f0.z); o.s[3] = f2bf(f0.w);
    o.s[4] = f2bf(f1.x); o.s[5] = f2bf(f1.y); o.s[6] = f2bf(f1.z); o.s[7] = f2bf(f1.w);
    *(int4*)(xT + (size_t)r * Vt + v) = o.q;
}

// ---------------- sentinel pre-fill (plain stores; kernel-end flush makes
// them visible to sc0sc1 readers -- proven by R7's mirror path) --------------
__global__ __launch_bounds__(256) void fill_kernel(unsigned short* __restrict__ h) {
    size_t i = ((size_t)blockIdx.x * 256u + threadIdx.x) * 16u;  // shorts
    i32x4 s = (i32x4){0x7FFF7FFF, 0x7FFF7FFF, 0x7FFF7FFF, 0x7FFF7FFF};
    *(i32x4*)(h + i) = s;
    *(i32x4*)(h + i + 8) = s;
}

// ---------------- persistent dataflow recurrence: 128 WGs ----------------
__global__ __launch_bounds__(256) void rec_kernel(
    const float* __restrict__ Wih1, const float* __restrict__ Whh1,
    const float* __restrict__ bih1, const float* __restrict__ bhh1,
    const float* __restrict__ Wih2, const float* __restrict__ Whh2,
    const float* __restrict__ bih2, const float* __restrict__ bhh2,
    const unsigned short* __restrict__ xT,
    unsigned short* h1s, unsigned short* h2s) {
    const int bid = blockIdx.x;
    const int layer = bid >> 6;
    const int cgrp = (bid >> 3) & 7;  // 32 h-cols [32cgrp, 32cgrp+32)
    const int bgrp = bid & 7;         // 16 batch rows [16bgrp, 16bgrp+16)

    const float* Win = layer ? Wih2 : Wih1;
    const float* Whh = layer ? Whh2 : Whh1;
    const float* bi = layer ? bih2 : bih1;
    const float* bh = layer ? bhh2 : bhh1;

    // local gate row r (0..127): global = 256*(r>>5) + 32*cgrp + (r&31)
    // row stride 264 shorts = 132 dw == 4 mod 32 -> <=2-way b128 conflicts
    __shared__ unsigned short sW[2][128][264];  // 132KB
    __shared__ float sG[4][16][36];             // gate exchange, padded
    __shared__ unsigned short sH[16][32];       // assembled h tile (1KB)

    const int tid = threadIdx.x;
    {   // stage both matrices: thread -> (row tid>>1, K-half tid&1)
        int row = tid >> 1, seg = (tid & 1) * 128;
        size_t grow = (size_t)(256 * (row >> 5) + 32 * cgrp + (row & 31)) * Vt + seg;
        for (int m = 0; m < 2; ++m) {
            const float* src = (m ? Whh : Win) + grow;
            unsigned short* dst = &sW[m][row][seg];
            for (int k = 0; k < 128; k += 4) {
                float4 f = *(const float4*)(src + k);
                dst[k + 0] = f2bf(f.x); dst[k + 1] = f2bf(f.y);
                dst[k + 2] = f2bf(f.z); dst[k + 3] = f2bf(f.w);
            }
        }
    }
    __syncthreads();

    const int lane = tid & 63;
    const int wv = tid >> 6;   // wave = GATE TYPE (0:i 1:f 2:g 3:o)
    const int q = lane >> 4;
    const int ln = lane & 15;

    float biasv[2];
#pragma unroll
    for (int n = 0; n < 2; ++n) {
        int grow = 256 * wv + 32 * cgrp + n * 16 + ln;
        biasv[n] = bi[grow] + bh[grow];
    }
    // cell state: thread handles (b = tid>>4, cols c0, c0+1)
    const int cb = tid >> 4;
    const int cc0 = (tid & 15) * 2;
    float cst[2] = {0.f, 0.f};

    const int aoff = ln * 32 + q * 8;            // within one 16x32 tile
    const size_t hbase = (size_t)bgrp * 4096 + aoff;
    const int xoff = (16 * bgrp + ln) * 256 + q * 8;  // xT row-major frag
    unsigned short* ob = layer ? h2s : h1s;
    // producer: ONE dwordx4 per lane, wave 0 only: tile = 512 shorts
    unsigned short* sptr = ob + (size_t)bgrp * 4096 + cgrp * 512 + lane * 8;

    for (int t = 0; t < Tt; ++t) {
        f32x4 acc[2];
        acc[0] = (f32x4){biasv[0], biasv[0], biasv[0], biasv[0]};
        acc[1] = (f32x4){biasv[1], biasv[1], biasv[1], biasv[1]};
        bf16x8 a1[8], a2[8];

        if (layer == 0) {
            // x loads FIRST (older in vmcnt FIFO -> x-GEMM need not wait on h)
            const unsigned short* xp = xT + (size_t)t * TS + xoff;
#pragma unroll
            for (int kb = 0; kb < 8; ++kb) a1[kb] = *(const bf16x8*)(xp + kb * 32);
            const unsigned short* hp = h1s + (size_t)(t - 1) * TS + hbase;
            if (t > 0) LD8T(a2, hp);
            // x-GEMM (waits only the x loads)
#pragma unroll
            for (int kb = 0; kb < 8; ++kb) {
                bf16x8 b0 = *(const bf16x8*)&sW[0][32 * wv + ln][kb * 32 + q * 8];
                bf16x8 b1 = *(const bf16x8*)&sW[0][32 * wv + 16 + ln][kb * 32 + q * 8];
                acc[0] = MFMA(a1[kb], b0, acc[0]);
                acc[1] = MFMA(a1[kb], b1, acc[1]);
            }
            if (t > 0) {
                for (;;) {  // sentinel poll: clean => operands already in regs
                    vm_drain();
                    int d = 0;
#pragma unroll
                    for (int kb = 0; kb < 8; ++kb) d |= fdirty(a2[kb]);
                    if (!__any(d)) break;
                    __builtin_amdgcn_s_sleep(1);
                    LD8T(a2, hp);
                }
#pragma unroll
                for (int kb = 0; kb < 8; ++kb) {
                    bf16x8 b0 = *(const bf16x8*)&sW[1][32 * wv + ln][kb * 32 + q * 8];
                    bf16x8 b1 = *(const bf16x8*)&sW[1][32 * wv + 16 + ln][kb * 32 + q * 8];
                    acc[0] = MFMA(a2[kb], b0, acc[0]);
                    acc[1] = MFMA(a2[kb], b1, acc[1]);
                }
            }
        } else {
            const unsigned short* hp1 = h1s + (size_t)t * TS + hbase;
            const unsigned short* hp2 = h2s + (size_t)(t - 1) * TS + hbase;
            LD8T(a1, hp1);
            if (t > 0) LD8T(a2, hp2);
            unsigned need = (t > 0) ? 3u : 1u;
            for (;;) {  // combined poll, one drain for both operand sets
                vm_drain();
                unsigned nm = 0;
                if (need & 1) {
                    int d = 0;
#pragma unroll
                    for (int kb = 0; kb < 8; ++kb) d |= fdirty(a1[kb]);
                    if (__any(d)) nm |= 1u;
                }
                if (need & 2) {
                    int d = 0;
#pragma unroll
                    for (int kb = 0; kb < 8; ++kb) d |= fdirty(a2[kb]);
                    if (__any(d)) nm |= 2u;
                }
                if (!nm) break;
                need = nm;
                __builtin_amdgcn_s_sleep(1);
                if (nm & 1) LD8T(a1, hp1);
                if (nm & 2) LD8T(a2, hp2);
            }
#pragma unroll
            for (int kb = 0; kb < 8; ++kb) {
                bf16x8 b0 = *(const bf16x8*)&sW[0][32 * wv + ln][kb * 32 + q * 8];
                bf16x8 b1 = *(const bf16x8*)&sW[0][32 * wv + 16 + ln][kb * 32 + q * 8];
                acc[0] = MFMA(a1[kb], b0, acc[0]);
                acc[1] = MFMA(a1[kb], b1, acc[1]);
            }
            if (t > 0) {
#pragma unroll
                for (int kb = 0; kb < 8; ++kb) {
                    bf16x8 b0 = *(const bf16x8*)&sW[1][32 * wv + ln][kb * 32 + q * 8];
                    bf16x8 b1 = *(const bf16x8*)&sW[1][32 * wv + 16 + ln][kb * 32 + q * 8];
                    acc[0] = MFMA(a2[kb], b0, acc[0]);
                    acc[1] = MFMA(a2[kb], b1, acc[1]);
                }
            }
        }

        // gate exchange: wave wv wrote gate type wv; acc[n][r] = gate for
        // (batch 4q+r, col n*16+ln)
#pragma unroll
        for (int n = 0; n < 2; ++n)
#pragma unroll
            for (int r = 0; r < 4; ++r) sG[wv][q * 4 + r][n * 16 + ln] = acc[n][r];
        __syncthreads();
        // cell: 2 h-values per thread
#pragma unroll
        for (int j = 0; j < 2; ++j) {
            int c = cc0 + j;
            float iv = sG[0][cb][c], fv = sG[1][cb][c];
            float gv = sG[2][cb][c], ov = sG[3][cb][c];
            float cval = sigm(fv) * cst[j] + sigm(iv) * tanh_f(gv);
            cst[j] = cval;
            sH[cb][c] = f2bf(sigm(ov) * tanh_f(cval));
        }
        __syncthreads();
        if (tid < 64) {  // ONE coalesced 1KB tile store by wave 0
            bf16x8 hv = *(const bf16x8*)((const unsigned short*)sH + tid * 8);
            unsigned short* dst = sptr + (size_t)t * TS;
            asm volatile("global_store_dwordx4 %0, %1, off sc0 sc1" ::"v"(dst),
                         "v"(hv) : "memory");
        }
    }
}

// ---------------- out[b,t,:] = h2s_tiled[t] @ w_n^T + fc_b ----------------
__global__ __launch_bounds__(256) void fc_kernel(const unsigned short* __restrict__ h2s,
                                                 const float* __restrict__ fcw,
                                                 const float* __restrict__ fcb,
                                                 float* __restrict__ out) {
    const int bid = blockIdx.x;
    const int rb = bid >> 2;  // t
    const int c0 = (bid & 3) * 64;
    __shared__ unsigned short sWf[64][264];
    __shared__ float sInv[64];
    const int tid = threadIdx.x;
    if (tid < 64) {
        const float* wr = fcw + (size_t)(c0 + tid) * 256;
        float s = 0.f;
        for (int k = 0; k < 256; k += 4) {
            float4 f = *(const float4*)(wr + k);
            s += f.x * f.x + f.y * f.y + f.z * f.z + f.w * f.w;
        }
        sInv[tid] = rsqrtf(s);
    }
    __syncthreads();
    {
        int lr = tid & 63, seg = tid >> 6;
        float inv = sInv[lr];
        const float* wr = fcw + (size_t)(c0 + lr) * 256 + seg * 64;
        unsigned short* dst = &sWf[lr][seg * 64];
        for (int k = 0; k < 64; k += 4) {
            float4 f = *(const float4*)(wr + k);
            dst[k + 0] = f2bf(f.x * inv); dst[k + 1] = f2bf(f.y * inv);
            dst[k + 2] = f2bf(f.z * inv); dst[k + 3] = f2bf(f.w * inv);
        }
    }
    __syncthreads();
    const int lane = tid & 63, w = tid >> 6, q = lane >> 4, ln = lane & 15;
    f32x4 acc[2][4];
    for (int rk = 0; rk < 2; ++rk)
        for (int nb = 0; nb < 4; ++nb) {
            float bv = fcb[c0 + nb * 16 + ln];
            acc[rk][nb] = (f32x4){bv, bv, bv, bv};
        }
    // tiled h2: [bgrp][cgrp][16][32]; wave w covers bgrps {2w, 2w+1}
    const unsigned short* P0 =
        h2s + (size_t)rb * TS + (2 * w) * 4096 + ln * 32 + q * 8;
    const unsigned short* P1 = P0 + 4096;
    for (int kb = 0; kb < 8; ++kb) {
        bf16x8 a0 = *(const bf16x8*)(P0 + kb * 512);
        bf16x8 a1 = *(const bf16x8*)(P1 + kb * 512);
        for (int nb = 0; nb < 4; ++nb) {
            bf16x8 b = *(const bf16x8*)&sWf[nb * 16 + ln][kb * 32 + q * 8];
            acc[0][nb] = MFMA(a0, b, acc[0][nb]);
            acc[1][nb] = MFMA(a1, b, acc[1][nb]);
        }
    }
    for (int rk = 0; rk < 2; ++rk)
        for (int nb = 0; nb < 4; ++nb)
            for (int r = 0; r < 4; ++r) {
                int bb = 32 * w + rk * 16 + q * 4 + r;
                int o = c0 + nb * 16 + ln;
                out[((size_t)bb * Tt + rb) * 256 + o] = acc[rk][nb][r];
            }
}

extern "C" void kernel_launch(void* const* d_in, const int* in_sizes, int n_in,
                              void* d_out, int out_size, void* d_ws, size_t ws_size,
                              hipStream_t stream) {
    const float* x    = (const float*)d_in[0];
    const float* Wih1 = (const float*)d_in[1];
    const float* Whh1 = (const float*)d_in[2];
    const float* bih1 = (const float*)d_in[3];
    const float* bhh1 = (const float*)d_in[4];
    const float* Wih2 = (const float*)d_in[5];
    const float* Whh2 = (const float*)d_in[6];
    const float* bih2 = (const float*)d_in[7];
    const float* bhh2 = (const float*)d_in[8];
    const float* fcw  = (const float*)d_in[9];
    const float* fcb  = (const float*)d_in[10];

    char* ws = (char*)d_ws;
    unsigned short* xT  = (unsigned short*)ws;         // 64MB
    unsigned short* h1s = xT + (size_t)Tt * TS;        // 64MB
    unsigned short* h2s = h1s + (size_t)Tt * TS;       // 64MB

    fill_kernel<<<16384, 256, 0, stream>>>(h1s);  // h1s+h2s contiguous 128MB
    cvt_kernel<<<16384, 256, 0, stream>>>(x, xT);
    rec_kernel<<<128, 256, 0, stream>>>(Wih1, Whh1, bih1, bhh1,
                                        Wih2, Whh2, bih2, bhh2,
                                        xT, h1s, h2s);
    fc_kernel<<<4096, 256, 0, stream>>>(h2s, fcw, fcb, (float*)d_out);
}